// Round 7
// baseline (454.191 us; speedup 1.0000x reference)
//
#include <hip/hip_runtime.h>
#include <math.h>

#define SDF_W      7000.0f
#define EIK_W      600.0f
#define ORI_W      500.0f
#define NEAR_ORI_W 10.0f
#define GRADN_W    200.0f

#define TILE   2048          // points per LDS tile (32 KB of float4)
#define NWAVE  8             // 512-thread blocks
#define QPL    8             // queries per lane -> 512 queries per block
#define CHK    64            // chunk granularity for index recovery (= wave size)
#define WS_REC 4096          // float offset of per-query records

// ws float layout:
//   [0..4]  : global accumulators ori/nori/sdf/eik/gn (zeroed by nn_scan blk 0)
//   [7]     : completion counter (uint, zeroed by nn_scan blk 0)
//   [4096..]: records, float4 per (query, split): {M1, M2, c1, c2}

__device__ __forceinline__ float nh2(float sx, float sy, float sz) {
    return -0.5f * fmaf(sx, sx, fmaf(sy, sy, sz * sz));
}
// Deterministic score; bit-identical chain in nn_scan and recover_k.
__device__ __forceinline__ float score(float qx, float qy, float qz,
                                       float sx, float sy, float sz, float nh) {
    return fmaf(qx, sx, fmaf(qy, sy, fmaf(qz, sz, nh)));
}

// ---------------------------------------------------------------------------
// Hot kernel (UNCHANGED from R6): top-2 score per (query, S-split) + chunk ids.
// ---------------------------------------------------------------------------
__global__ __launch_bounds__(512, 4) void nn_scan(
    const float* __restrict__ offq, const float* __restrict__ nearq,
    const float* __restrict__ surf,
    float* __restrict__ ws, int S, int Qoff, int QT, int splits, int segLen)
{
    __shared__ float4 tile[TILE];                 // 32 KB; reused for merge recs
    const int t    = threadIdx.x;
    const int lane = t & 63;
    const int wv   = __builtin_amdgcn_readfirstlane(t >> 6);   // 0..7

    if (blockIdx.x == 0 && t < 8) ws[t] = 0.0f;   // zero accumulators + counter

    const int qg = blockIdx.x / splits;
    const int sp = blockIdx.x % splits;
    const int sb = sp * segLen;
    int se = sb + segLen; if (se > S) se = S;

    // ---- load 8 queries per lane ----
    float qx[QPL], qy[QPL], qz[QPL];
    #pragma unroll
    for (int k = 0; k < QPL; ++k) {
        int q = qg * 512 + k * 64 + lane;
        float x = 0.f, y = 0.f, z = 0.f;
        if (q < QT) {
            const float* p = (q < Qoff) ? (offq + 3 * q) : (nearq + 3 * (q - Qoff));
            x = p[0]; y = p[1]; z = p[2];
        }
        qx[k] = x; qy[k] = y; qz[k] = z;
    }

    float M1[QPL], M2[QPL], P1[QPL], P2[QPL];
    int   c1[QPL], c2[QPL];
    const int cinit = (sb < S ? sb : 0) >> 6;
    #pragma unroll
    for (int k = 0; k < QPL; ++k) {
        M1[k] = -3.0e38f; M2[k] = -3.0e38f;
        P1[k] = -3.0e38f; P2[k] = -3.0e38f;
        c1[k] = cinit;    c2[k] = cinit;
    }

    for (int base = sb; base < se; base += TILE) {
        __syncthreads();
        // stage TILE points lane-contiguous (coalesced + conflict-free)
        #pragma unroll
        for (int k = 0; k < TILE / 512; ++k) {
            int li = k * 512 + t;
            int p  = base + li;
            float sx = 0.f, sy = 0.f, sz = 0.f, w = -3.0e38f;
            if (p < se) {
                sx = surf[3*p]; sy = surf[3*p+1]; sz = surf[3*p+2];
                w  = nh2(sx, sy, sz);
            }
            tile[li] = make_float4(sx, sy, sz, w);
        }
        __syncthreads();
        // scan: wave wv covers 256 pts = 4 chunks of 64
        const int lo = wv * (TILE / NWAVE);
        const float4* tp = tile + lo;
        const int cidbase = (base + lo) >> 6;                 // wave-uniform
        #pragma unroll 1
        for (int c = 0; c < (TILE / NWAVE) / CHK; ++c) {
            const float4* cp = tp + c * CHK;
            #pragma unroll 8
            for (int o = 0; o < CHK; ++o) {
                float4 s4 = cp[o];                            // broadcast b128
                #pragma unroll
                for (int k = 0; k < QPL; ++k) {
                    float g = score(qx[k], qy[k], qz[k], s4.x, s4.y, s4.z, s4.w);
                    M2[k] = __builtin_amdgcn_fmed3f(g, M1[k], M2[k]);
                    M1[k] = fmaxf(M1[k], g);
                }
            }
            const int cid = cidbase + c;
            #pragma unroll
            for (int k = 0; k < QPL; ++k) {
                int oc1 = c1[k];
                // M2 change sourced from M1-demotion (M2==old M1) inherits c1.
                c2[k] = (M2[k] != P2[k]) ? ((M2[k] == P1[k]) ? oc1 : cid) : c2[k];
                c1[k] = (M1[k] != P1[k]) ? cid : oc1;
                P1[k] = M1[k]; P2[k] = M2[k];
            }
        }
    }

    // ---- hierarchical 8-wave merge in 32 KB LDS (tile reused) ----
    float4* rec = tile;
    #pragma unroll
    for (int stage = 4; stage >= 1; stage >>= 1) {
        __syncthreads();
        if (wv >= stage && wv < 2 * stage) {
            #pragma unroll
            for (int k = 0; k < QPL; ++k)
                rec[(wv - stage) * 512 + k * 64 + lane] =
                    make_float4(M1[k], M2[k], __int_as_float(c1[k]), __int_as_float(c2[k]));
        }
        __syncthreads();
        if (wv < stage) {
            #pragma unroll
            for (int k = 0; k < QPL; ++k) {
                float4 a = rec[wv * 512 + k * 64 + lane];
                float a1 = a.x, a2 = a.y;
                int ac1 = __float_as_int(a.z), ac2 = __float_as_int(a.w);
                if (a1 > M1[k])      { M2[k] = M1[k]; c2[k] = c1[k]; M1[k] = a1; c1[k] = ac1; }
                else if (a1 > M2[k]) { M2[k] = a1; c2[k] = ac1; }
                if (a2 > M2[k])      { M2[k] = a2; c2[k] = ac2; }
            }
        }
    }
    if (wv == 0) {
        #pragma unroll
        for (int k = 0; k < QPL; ++k) {
            int gq = qg * 512 + k * 64 + lane;
            if (gq < QT)
                ((float4*)(ws + WS_REC))[(size_t)gq * splits + sp] =
                    make_float4(M1[k], M2[k], __int_as_float(c1[k]), __int_as_float(c2[k]));
        }
    }
}

// ---------------------------------------------------------------------------
// Recovery: ONE WAVE PER QUERY (32768 waves) — short dependency chain per
// wave, massive TLP to hide load latency (R6's 8-queries-per-wave serial loop
// was latency-bound at 9.5% VALUBusy). 64 lanes check both tracked chunks in
// one memory round; ballot+ctz+shfl extracts the matching lane's dot.
// Small losses fused (wave shfl-reduce); last block finalizes via counter.
// ---------------------------------------------------------------------------
__global__ __launch_bounds__(512) void recover_k(
    const float* __restrict__ offq, const float* __restrict__ nearq,
    const float* __restrict__ surf, const float* __restrict__ norms,
    const float* __restrict__ nmpred, const float* __restrict__ nppred,
    const float* __restrict__ mp, const float* __restrict__ mg,
    const float* __restrict__ sn,
    float* __restrict__ ws, float* __restrict__ out,
    int S, int Qoff, int QT, int N, int splits, int Qnear)
{
    const int t    = threadIdx.x;
    const int lane = t & 63;
    const int wv   = __builtin_amdgcn_readfirstlane(t >> 6);   // 0..7
    const int q    = blockIdx.x * 8 + wv;                      // one query/wave

    float term = 0.f;
    bool  isNear = false;
    if (q < QT) {                                              // wave-uniform
        // merge split records (independent loads, issued together)
        const float4* recs = ((const float4*)(ws + WS_REC)) + (size_t)q * splits;
        float4 r = recs[0];
        float M1 = r.x, M2 = r.y;
        int C1 = __float_as_int(r.z), C2 = __float_as_int(r.w);
        for (int i = 1; i < splits; ++i) {
            float4 a = recs[i];
            float a1 = a.x, a2 = a.y;
            int ac1 = __float_as_int(a.z), ac2 = __float_as_int(a.w);
            if (a1 > M1)      { M2 = M1; C2 = C1; M1 = a1; C1 = ac1; }
            else if (a1 > M2) { M2 = a1; C2 = ac1; }
            if (a2 > M2)      { M2 = a2; C2 = ac2; }
        }
        isNear = (q >= Qoff);
        const float* qp = isNear ? (nearq + 3 * (q - Qoff)) : (offq + 3 * q);
        const float qx = qp[0], qy = qp[1], qz = qp[2];
        const float pred = isNear ? nppred[q - Qoff] : nmpred[q];

        // one round: points + normals of both chunks (independent loads)
        int j1 = C1 * CHK + lane;
        int j2 = C2 * CHK + lane;
        float g1 = -3.0e38f, d1l = 0.f, g2 = -3.0e38f, d2l = 0.f;
        if (j1 < S) {
            float sx = surf[3*j1], sy = surf[3*j1+1], sz = surf[3*j1+2];
            float nx = norms[3*j1], ny = norms[3*j1+1], nz = norms[3*j1+2];
            g1  = score(qx, qy, qz, sx, sy, sz, nh2(sx, sy, sz));
            d1l = (qx - sx) * nx + (qy - sy) * ny + (qz - sz) * nz;
        }
        if (j2 < S) {
            float sx = surf[3*j2], sy = surf[3*j2+1], sz = surf[3*j2+2];
            float nx = norms[3*j2], ny = norms[3*j2+1], nz = norms[3*j2+2];
            g2  = score(qx, qy, qz, sx, sy, sz, nh2(sx, sy, sz));
            d2l = (qx - sx) * nx + (qy - sy) * ny + (qz - sz) * nz;
        }
        unsigned long long mk1 = __ballot(g1 == M1);
        int lane1 = mk1 ? (int)__builtin_ctzll(mk1) : 0;
        float d1 = __shfl(d1l, lane1);
        unsigned long long mk2 = __ballot(g2 == M2);
        if (C1 == C2 && mk1) mk2 &= ~(1ull << lane1);          // distinct indices
        float d2 = mk2 ? __shfl(d2l, (int)__builtin_ctzll(mk2)) : d1;

        float ms  = d1 + d2;                                   // sign(mean)==sign(sum)
        float sgn = (ms > 0.f) ? 1.f : ((ms < 0.f) ? -1.f : 0.f);
        term = fmaxf(0.f, -pred * sgn);
    }

    // fused small losses (grid covers N in the first blocks)
    float sdf = 0.f, eik = 0.f, gn = 0.f;
    const int gid = blockIdx.x * 512 + t;
    const int GT  = gridDim.x * 512;
    for (int i = gid; i < N; i += GT) {
        float p = mp[i];
        sdf += p * p;
        float gx = mg[3*i], gy = mg[3*i+1], gz = mg[3*i+2];
        float nrm = sqrtf(fmaf(gx, gx, fmaf(gy, gy, gz * gz)));
        float d = nrm - 1.0f;
        eik += d * d;
        float nx = sn[3*i], ny = sn[3*i+1], nz = sn[3*i+2];
        float dx = gx - nx, dy = gy - ny, dz = gz - nz;
        gn += fmaf(dx, dx, fmaf(dy, dy, dz * dz));
    }
    // wave shfl-reduce (only waves that touched data have nonzero)
    if (blockIdx.x * 512 + wv * 64 < N) {
        #pragma unroll
        for (int off = 32; off > 0; off >>= 1) {
            sdf += __shfl_down(sdf, off);
            eik += __shfl_down(eik, off);
            gn  += __shfl_down(gn,  off);
        }
    }

    __shared__ float sb[5][NWAVE];
    if (lane == 0) {
        sb[0][wv] = isNear ? 0.f : term;
        sb[1][wv] = isNear ? term : 0.f;
        sb[2][wv] = sdf; sb[3][wv] = eik; sb[4][wv] = gn;
    }
    __syncthreads();
    if (t == 0) {
        float a0 = 0.f, a1 = 0.f, a2 = 0.f, a3 = 0.f, a4 = 0.f;
        #pragma unroll
        for (int w = 0; w < NWAVE; ++w) {
            a0 += sb[0][w]; a1 += sb[1][w]; a2 += sb[2][w];
            a3 += sb[3][w]; a4 += sb[4][w];
        }
        atomicAdd(&ws[0], a0); atomicAdd(&ws[1], a1); atomicAdd(&ws[2], a2);
        atomicAdd(&ws[3], a3); atomicAdd(&ws[4], a4);
        __threadfence();
        unsigned old = atomicAdd((unsigned*)ws + 7, 1u);
        if (old == gridDim.x - 1) {            // last block finalizes
            float orim  = atomicAdd(&ws[0], 0.f) / (float)Qoff;
            float norim = atomicAdd(&ws[1], 0.f) / (float)Qnear;
            float sdfm  = atomicAdd(&ws[2], 0.f) / (float)N;
            float eikm  = atomicAdd(&ws[3], 0.f) / (float)N;
            float gnm   = atomicAdd(&ws[4], 0.f) / (3.0f * (float)N);
            out[0] = SDF_W * sdfm + EIK_W * eikm + ORI_W * orim
                   + NEAR_ORI_W * norim + GRADN_W * gnm;
            out[1] = sdfm;
            out[2] = eikm;
            out[3] = orim;
            out[4] = norim;
            out[5] = gnm;
        }
    }
}

extern "C" void kernel_launch(void* const* d_in, const int* in_sizes, int n_in,
                              void* d_out, int out_size, void* d_ws, size_t ws_size,
                              hipStream_t stream)
{
    const float* mp    = (const float*)d_in[0];  // manifold_pred      [N,1]
    const float* mg    = (const float*)d_in[1];  // manifold_grad      [N,3]
    const float* nmp   = (const float*)d_in[2];  // nonmanifold_pred   [N,1]
    const float* npp   = (const float*)d_in[3];  // near_points_pred   [N,1]
    const float* sp    = (const float*)d_in[4];  // surface_points     [S,3]
    const float* sn    = (const float*)d_in[5];  // surface_normals    [S,3]
    const float* offp  = (const float*)d_in[6];  // off_surface_points [Q,3]
    const float* nearp = (const float*)d_in[7];  // near_points        [Q,3]
    float* out = (float*)d_out;

    const int N     = in_sizes[0];
    const int S     = in_sizes[4] / 3;
    const int Qoff  = in_sizes[2];
    const int Qnear = in_sizes[3];
    const int QT    = Qoff + Qnear;

    float* ws = (float*)d_ws;

    const int qgroups = (QT + 511) / 512;
    size_t need8 = (size_t)WS_REC * 4 + (size_t)QT * 8 * 16 + 1024;
    size_t need4 = (size_t)WS_REC * 4 + (size_t)QT * 4 * 16 + 1024;
    const int splits = (ws_size >= need8) ? 8 : ((ws_size >= need4) ? 4 : 2);
    const int segLen = (((S + splits - 1) / splits) + CHK - 1) / CHK * CHK;

    const int RB = (QT + 7) / 8;                // one wave per query
    nn_scan<<<qgroups * splits, 512, 0, stream>>>(offp, nearp, sp, ws,
                                                  S, Qoff, QT, splits, segLen);
    recover_k<<<RB, 512, 0, stream>>>(offp, nearp, sp, sn, nmp, npp,
                                      mp, mg, sn, ws, out, S, Qoff, QT, N,
                                      splits, Qnear);
}

// Round 8
// 171.596 us; speedup vs baseline: 2.6469x; 2.6469x over previous
//
#include <hip/hip_runtime.h>
#include <math.h>

#define SDF_W      7000.0f
#define EIK_W      600.0f
#define ORI_W      500.0f
#define NEAR_ORI_W 10.0f
#define GRADN_W    200.0f

#define TILE   2048          // points per LDS tile (32 KB of float4)
#define NWAVE  8             // 512-thread blocks
#define QPL    8             // queries per lane -> 512 queries per block
#define CHK    64            // chunk granularity for index recovery (= wave size)
#define PSTRIDE 4096         // per-array stride (floats) for block partials
#define WS_REC 20480         // float offset of records (= 5*PSTRIDE)

typedef float v2f __attribute__((ext_vector_type(2)));

// ws float layout:
//   [k*PSTRIDE + b] : recover-block partials, k = 0:ori 1:nori 2:sdf 3:eik 4:gn
//   [WS_REC ...]    : records, float4 per (query, split): {M1, M2, c1, c2}

__device__ __forceinline__ float nh2(float sx, float sy, float sz) {
    return -0.5f * fmaf(sx, sx, fmaf(sy, sy, sz * sz));
}
// Deterministic score; bit-identical chain in nn_scan and recover_k.
__device__ __forceinline__ float score(float qx, float qy, float qz,
                                       float sx, float sy, float sz, float nh) {
    return fmaf(qx, sx, fmaf(qy, sy, fmaf(qz, sz, nh)));
}

// ---------------------------------------------------------------------------
// Hot kernel: top-2 score per (query, S-split) + chunk ids.
// Fully packed inner loop (v_pk_fma/pk_min/pk_max): 6 instrs per 2 queries
// per point. amdgpu_waves_per_eu(4,4) pins the allocator at the 128-VGPR
// budget that 2 blocks/CU allows (R5's (512,4) squeezed to 56 regs + parking).
// ---------------------------------------------------------------------------
__global__ __launch_bounds__(512)
__attribute__((amdgpu_waves_per_eu(4, 4)))
void nn_scan(
    const float* __restrict__ offq, const float* __restrict__ nearq,
    const float* __restrict__ surf,
    float* __restrict__ ws, int S, int Qoff, int QT, int splits, int segLen)
{
    __shared__ float4 tile[TILE];                 // 32 KB; reused for merge recs
    const int t    = threadIdx.x;
    const int lane = t & 63;
    const int wv   = __builtin_amdgcn_readfirstlane(t >> 6);   // 0..7

    const int qg = blockIdx.x / splits;
    const int sp = blockIdx.x % splits;
    const int sb = sp * segLen;
    int se = sb + segLen; if (se > S) se = S;

    // ---- load 8 queries per lane, packed 2-wide ----
    v2f qx2[QPL/2], qy2[QPL/2], qz2[QPL/2];
    #pragma unroll
    for (int p = 0; p < QPL/2; ++p) {
        float xs[2], ys[2], zs[2];
        #pragma unroll
        for (int h = 0; h < 2; ++h) {
            int q = qg * 512 + (2*p + h) * 64 + lane;
            float x = 0.f, y = 0.f, z = 0.f;
            if (q < QT) {
                const float* pp = (q < Qoff) ? (offq + 3 * q) : (nearq + 3 * (q - Qoff));
                x = pp[0]; y = pp[1]; z = pp[2];
            }
            xs[h] = x; ys[h] = y; zs[h] = z;
        }
        qx2[p] = (v2f){xs[0], xs[1]};
        qy2[p] = (v2f){ys[0], ys[1]};
        qz2[p] = (v2f){zs[0], zs[1]};
    }

    v2f  M1[QPL/2], M2[QPL/2];
    float P1[QPL], P2[QPL];
    int  c1[QPL], c2[QPL];
    const int cinit = (sb < S ? sb : 0) >> 6;
    #pragma unroll
    for (int p = 0; p < QPL/2; ++p) {
        M1[p] = (v2f){-3.0e38f, -3.0e38f};
        M2[p] = (v2f){-3.0e38f, -3.0e38f};
    }
    #pragma unroll
    for (int k = 0; k < QPL; ++k) {
        P1[k] = -3.0e38f; P2[k] = -3.0e38f;
        c1[k] = cinit;    c2[k] = cinit;
    }

    for (int base = sb; base < se; base += TILE) {
        __syncthreads();
        // stage TILE points lane-contiguous (coalesced + conflict-free)
        #pragma unroll
        for (int k = 0; k < TILE / 512; ++k) {
            int li = k * 512 + t;
            int p  = base + li;
            float sx = 0.f, sy = 0.f, sz = 0.f, w = -3.0e38f;
            if (p < se) {
                sx = surf[3*p]; sy = surf[3*p+1]; sz = surf[3*p+2];
                w  = nh2(sx, sy, sz);
            }
            tile[li] = make_float4(sx, sy, sz, w);
        }
        __syncthreads();
        // scan: wave wv covers 256 pts = 4 chunks of 64
        const int lo = wv * (TILE / NWAVE);
        const int cidbase = (base + lo) >> 6;                 // wave-uniform
        #pragma unroll 1
        for (int c = 0; c < (TILE / NWAVE) / CHK; ++c) {
            const float4* cp = tile + lo + c * CHK;
            #pragma unroll 8
            for (int o = 0; o < CHK; ++o) {
                float4 s4 = cp[o];                            // broadcast b128
                v2f sx = (v2f){s4.x, s4.x};
                v2f sy = (v2f){s4.y, s4.y};
                v2f sz = (v2f){s4.z, s4.z};
                v2f sw = (v2f){s4.w, s4.w};
                #pragma unroll
                for (int p = 0; p < QPL/2; ++p) {
                    v2f g = __builtin_elementwise_fma(qx2[p], sx,
                            __builtin_elementwise_fma(qy2[p], sy,
                            __builtin_elementwise_fma(qz2[p], sz, sw)));
                    M2[p] = __builtin_elementwise_max(M2[p],
                            __builtin_elementwise_min(g, M1[p]));
                    M1[p] = __builtin_elementwise_max(M1[p], g);
                }
            }
            const int cid = cidbase + c;
            #pragma unroll
            for (int k = 0; k < QPL; ++k) {
                float m1 = M1[k/2][k&1], m2 = M2[k/2][k&1];
                int oc1 = c1[k];
                // M2 change whose new value equals old M1 inherits c1
                // (value-correct: old M1's point carries that score there).
                c2[k] = (m2 != P2[k]) ? ((m2 == P1[k]) ? oc1 : cid) : c2[k];
                c1[k] = (m1 != P1[k]) ? cid : oc1;
                P1[k] = m1; P2[k] = m2;
            }
        }
    }

    // ---- hierarchical 8-wave merge in 32 KB LDS (tile reused) ----
    float m1s[QPL], m2s[QPL];
    #pragma unroll
    for (int k = 0; k < QPL; ++k) { m1s[k] = M1[k/2][k&1]; m2s[k] = M2[k/2][k&1]; }

    float4* rec = tile;
    #pragma unroll
    for (int stage = 4; stage >= 1; stage >>= 1) {
        __syncthreads();
        if (wv >= stage && wv < 2 * stage) {
            #pragma unroll
            for (int k = 0; k < QPL; ++k)
                rec[(wv - stage) * 512 + k * 64 + lane] =
                    make_float4(m1s[k], m2s[k], __int_as_float(c1[k]), __int_as_float(c2[k]));
        }
        __syncthreads();
        if (wv < stage) {
            #pragma unroll
            for (int k = 0; k < QPL; ++k) {
                float4 a = rec[wv * 512 + k * 64 + lane];
                float a1 = a.x, a2 = a.y;
                int ac1 = __float_as_int(a.z), ac2 = __float_as_int(a.w);
                if (a1 > m1s[k])      { m2s[k] = m1s[k]; c2[k] = c1[k]; m1s[k] = a1; c1[k] = ac1; }
                else if (a1 > m2s[k]) { m2s[k] = a1; c2[k] = ac1; }
                if (a2 > m2s[k])      { m2s[k] = a2; c2[k] = ac2; }
            }
        }
    }
    if (wv == 0) {
        #pragma unroll
        for (int k = 0; k < QPL; ++k) {
            int gq = qg * 512 + k * 64 + lane;
            if (gq < QT)
                ((float4*)(ws + WS_REC))[(size_t)gq * splits + sp] =
                    make_float4(m1s[k], m2s[k], __int_as_float(c1[k]), __int_as_float(c2[k]));
        }
    }
}

// ---------------------------------------------------------------------------
// Recovery: one wave per query (TLP hides all load latency). NO atomics, NO
// fence (R7's same-line atomic finalize serialized the whole grid at ~80 ns
// per block): per-block partials to distinct ws slots; final_k reduces.
// ---------------------------------------------------------------------------
__global__ __launch_bounds__(512) void recover_k(
    const float* __restrict__ offq, const float* __restrict__ nearq,
    const float* __restrict__ surf, const float* __restrict__ norms,
    const float* __restrict__ nmpred, const float* __restrict__ nppred,
    const float* __restrict__ mp, const float* __restrict__ mg,
    const float* __restrict__ sn,
    float* __restrict__ ws, int S, int Qoff, int QT, int N, int splits)
{
    const int t    = threadIdx.x;
    const int lane = t & 63;
    const int wv   = __builtin_amdgcn_readfirstlane(t >> 6);   // 0..7
    const int q    = blockIdx.x * 8 + wv;                      // one query/wave

    float term = 0.f;
    bool  isNear = false;
    if (q < QT) {                                              // wave-uniform
        const float4* recs = ((const float4*)(ws + WS_REC)) + (size_t)q * splits;
        float4 r = recs[0];
        float M1 = r.x, M2 = r.y;
        int C1 = __float_as_int(r.z), C2 = __float_as_int(r.w);
        for (int i = 1; i < splits; ++i) {
            float4 a = recs[i];
            float a1 = a.x, a2 = a.y;
            int ac1 = __float_as_int(a.z), ac2 = __float_as_int(a.w);
            if (a1 > M1)      { M2 = M1; C2 = C1; M1 = a1; C1 = ac1; }
            else if (a1 > M2) { M2 = a1; C2 = ac1; }
            if (a2 > M2)      { M2 = a2; C2 = ac2; }
        }
        isNear = (q >= Qoff);
        const float* qp = isNear ? (nearq + 3 * (q - Qoff)) : (offq + 3 * q);
        const float qx = qp[0], qy = qp[1], qz = qp[2];
        const float pred = isNear ? nppred[q - Qoff] : nmpred[q];

        int j1 = C1 * CHK + lane;
        int j2 = C2 * CHK + lane;
        float g1 = -3.0e38f, d1l = 0.f, g2 = -3.0e38f, d2l = 0.f;
        if (j1 < S) {
            float sx = surf[3*j1], sy = surf[3*j1+1], sz = surf[3*j1+2];
            float nx = norms[3*j1], ny = norms[3*j1+1], nz = norms[3*j1+2];
            g1  = score(qx, qy, qz, sx, sy, sz, nh2(sx, sy, sz));
            d1l = (qx - sx) * nx + (qy - sy) * ny + (qz - sz) * nz;
        }
        if (j2 < S) {
            float sx = surf[3*j2], sy = surf[3*j2+1], sz = surf[3*j2+2];
            float nx = norms[3*j2], ny = norms[3*j2+1], nz = norms[3*j2+2];
            g2  = score(qx, qy, qz, sx, sy, sz, nh2(sx, sy, sz));
            d2l = (qx - sx) * nx + (qy - sy) * ny + (qz - sz) * nz;
        }
        unsigned long long mk1 = __ballot(g1 == M1);
        int lane1 = mk1 ? (int)__builtin_ctzll(mk1) : 0;
        float d1 = __shfl(d1l, lane1);
        unsigned long long mk2 = __ballot(g2 == M2);
        if (C1 == C2 && mk1) mk2 &= ~(1ull << lane1);          // distinct indices
        float d2 = mk2 ? __shfl(d2l, (int)__builtin_ctzll(mk2)) : d1;

        float ms  = d1 + d2;                                   // sign(mean)==sign(sum)
        float sgn = (ms > 0.f) ? 1.f : ((ms < 0.f) ? -1.f : 0.f);
        term = fmaxf(0.f, -pred * sgn);
    }

    // fused small losses (only the first ceil(N/512) blocks iterate)
    float sdf = 0.f, eik = 0.f, gn = 0.f;
    const int gid = blockIdx.x * 512 + t;
    const int GT  = gridDim.x * 512;
    for (int i = gid; i < N; i += GT) {
        float p = mp[i];
        sdf += p * p;
        float gx = mg[3*i], gy = mg[3*i+1], gz = mg[3*i+2];
        float nrm = sqrtf(fmaf(gx, gx, fmaf(gy, gy, gz * gz)));
        float d = nrm - 1.0f;
        eik += d * d;
        float nx = sn[3*i], ny = sn[3*i+1], nz = sn[3*i+2];
        float dx = gx - nx, dy = gy - ny, dz = gz - nz;
        gn += fmaf(dx, dx, fmaf(dy, dy, dz * dz));
    }
    if (blockIdx.x * 512 + wv * 64 < N) {      // waves that touched data
        #pragma unroll
        for (int off = 32; off > 0; off >>= 1) {
            sdf += __shfl_down(sdf, off);
            eik += __shfl_down(eik, off);
            gn  += __shfl_down(gn,  off);
        }
    }

    __shared__ float sb[5][NWAVE];
    if (lane == 0) {
        sb[0][wv] = isNear ? 0.f : term;
        sb[1][wv] = isNear ? term : 0.f;
        sb[2][wv] = sdf; sb[3][wv] = eik; sb[4][wv] = gn;
    }
    __syncthreads();
    if (t == 0) {
        float a[5] = {0.f, 0.f, 0.f, 0.f, 0.f};
        #pragma unroll
        for (int w = 0; w < NWAVE; ++w) {
            a[0] += sb[0][w]; a[1] += sb[1][w]; a[2] += sb[2][w];
            a[3] += sb[3][w]; a[4] += sb[4][w];
        }
        #pragma unroll
        for (int k = 0; k < 5; ++k) ws[k * PSTRIDE + blockIdx.x] = a[k];
    }
}

// ---------------------------------------------------------------------------
__global__ __launch_bounds__(256) void final_k(
    const float* __restrict__ ws, float* __restrict__ out,
    int N, int RB, int Qoff, int Qnear)
{
    __shared__ float r[5][256];
    int t = threadIdx.x;
    float s[5] = {0.f, 0.f, 0.f, 0.f, 0.f};
    for (int i = t; i < RB; i += 256) {
        #pragma unroll
        for (int k = 0; k < 5; ++k) s[k] += ws[k * PSTRIDE + i];
    }
    #pragma unroll
    for (int k = 0; k < 5; ++k) r[k][t] = s[k];
    __syncthreads();
    for (int off = 128; off > 0; off >>= 1) {
        if (t < off) {
            #pragma unroll
            for (int k = 0; k < 5; ++k) r[k][t] += r[k][t + off];
        }
        __syncthreads();
    }
    if (t == 0) {
        float orim  = r[0][0] / (float)Qoff;
        float norim = r[1][0] / (float)Qnear;
        float sdfm  = r[2][0] / (float)N;
        float eikm  = r[3][0] / (float)N;
        float gnm   = r[4][0] / (3.0f * (float)N);
        out[0] = SDF_W * sdfm + EIK_W * eikm + ORI_W * orim
               + NEAR_ORI_W * norim + GRADN_W * gnm;
        out[1] = sdfm;
        out[2] = eikm;
        out[3] = orim;
        out[4] = norim;
        out[5] = gnm;
    }
}

extern "C" void kernel_launch(void* const* d_in, const int* in_sizes, int n_in,
                              void* d_out, int out_size, void* d_ws, size_t ws_size,
                              hipStream_t stream)
{
    const float* mp    = (const float*)d_in[0];  // manifold_pred      [N,1]
    const float* mg    = (const float*)d_in[1];  // manifold_grad      [N,3]
    const float* nmp   = (const float*)d_in[2];  // nonmanifold_pred   [N,1]
    const float* npp   = (const float*)d_in[3];  // near_points_pred   [N,1]
    const float* sp    = (const float*)d_in[4];  // surface_points     [S,3]
    const float* sn    = (const float*)d_in[5];  // surface_normals    [S,3]
    const float* offp  = (const float*)d_in[6];  // off_surface_points [Q,3]
    const float* nearp = (const float*)d_in[7];  // near_points        [Q,3]
    float* out = (float*)d_out;

    const int N     = in_sizes[0];
    const int S     = in_sizes[4] / 3;
    const int Qoff  = in_sizes[2];
    const int Qnear = in_sizes[3];
    const int QT    = Qoff + Qnear;

    float* ws = (float*)d_ws;

    const int qgroups = (QT + 511) / 512;
    size_t need8 = ((size_t)WS_REC + (size_t)QT * 8 * 4) * 4 + 1024;
    size_t need4 = ((size_t)WS_REC + (size_t)QT * 4 * 4) * 4 + 1024;
    const int splits = (ws_size >= need8) ? 8 : ((ws_size >= need4) ? 4 : 2);
    const int segLen = (((S + splits - 1) / splits) + CHK - 1) / CHK * CHK;

    const int RB = (QT + 7) / 8;                // one wave per query
    nn_scan<<<qgroups * splits, 512, 0, stream>>>(offp, nearp, sp, ws,
                                                  S, Qoff, QT, splits, segLen);
    recover_k<<<RB, 512, 0, stream>>>(offp, nearp, sp, sn, nmp, npp,
                                      mp, mg, sn, ws, S, Qoff, QT, N, splits);
    final_k<<<1, 256, 0, stream>>>(ws, out, N, RB, Qoff, Qnear);
}